// Round 11
// baseline (4936.699 us; speedup 1.0000x reference)
//
#include <hip/hip_runtime.h>
#include <math.h>

typedef unsigned long long ull;

// LTC liquid scan — DUAL-STREAM interleaved pipeline.
// Rounds 8/9/10 proved the per-unfold exchange RT (~2.4K cy) is irreducible
// for a single stream (traffic/placement/detection all null or worse). Fix:
// hide it under an INDEPENDENT recurrence. Each block owns TWO batch-tiles
// (bt_A=2p, bt_B=2p+1; BT=2 each) x NTL=64 neurons; grid 256 = 32 pairs x
// 8 nt; 1 block/CU (LDS ~96 KB), co-resident => spin-safe.
// Schedule per kk (version v for both streams):
//   CHECK_A(stage x_A[v-1], regs prefetched) | BAR1 | ISSUE_B + GEMV_A |
//   BAR2 (pB drains under GEMV_A) | finish_A || CHECK_B | BAR3 |
//   ISSUE_A + GEMV_B | BAR4 (pA drains under GEMV_B) | finish_B
// Poll loads issue one phase early; by check time the producer published
// ~1.5K cy ago -> fresh on first look; guarded sleep re-poll for skew tails.
// Per-unfold FMA/LDS/publish totals identical to round-4; summation order
// identical -> absmax fingerprint 7.430939e16 expected.
// Kept: versioned 2-slot mailbox (RELAXED agent atomics; per-stream
// induction unchanged), local bypass (finish writes own 64-n segment to
// xsh; only remote segments polled), XOR f4-group swizzle everywhere.

#define NN 512
#define FF 256
#define KK 6
#define TT 256
#define NTL 64       // neurons per tile

#define DOT4(a, v) ((a).x * (v).x + (a).y * (v).y + (a).z * (v).z + (a).w * (v).w)
#define MLOAD(q) __hip_atomic_load((q), __ATOMIC_RELAXED, __HIP_MEMORY_SCOPE_AGENT)
#define MSTORE(q, x) __hip_atomic_store((q), (x), __ATOMIC_RELAXED, __HIP_MEMORY_SCOPE_AGENT)

__global__ __launch_bounds__(512, 2) void liquid_kernel(
    const float* __restrict__ I,     // [B][T][F]
    const float* __restrict__ DT,    // [B][T]
    const float* __restrict__ Wrec,  // [N][N]
    const float* __restrict__ Win,   // [N][F]
    const float* __restrict__ bv, const float* __restrict__ Av,
    const float* __restrict__ tauv,
    ull* __restrict__ mbx,           // [64 bt][2 slot][2 b][512 n] versioned
    float* __restrict__ out)         // [B][T][N]
{
  __shared__ __align__(16) float lds[24088];  // 96.4 KB -> 1 block/CU
  float* xshA = lds;                  // [2 b][512 n], swizzled f4 groups
  float* xshB = lds + 1024;           // [2 b][512 n]
  float* iro  = lds + 2048;           // [4 rows][260] input rows, swizzled
  float* wi   = iro + 4 * 260;        // [64][260] W_in slice, swizzled
  float* par  = wi + 64 * 260;        // [256][17]; parA=par, parB=par+128*17
  float* dts  = par + 256 * 17;       // [4] dt/K per batch row

  const int blk = blockIdx.x;
  const int p   = blk >> 3;          // batch-tile pair (32)
  const int nt  = blk & 7;           // neuron tile (8)
  const int tid = threadIdx.x;
  const int kc  = tid & 15;          // k-chunk (32 k each)
  const int nq  = tid >> 4;          // n-pair (2 n each), 0..31
  const int n0g = nt * NTL;          // global n base
  const int btA = 2 * p, btB = 2 * p + 1;

  // ---- W_rec slice: wv[r][j] = Wrec[n0g+2nq+r][32kc+4j .. +3] (64 VGPR) ----
  float4 wv[2][8];
  #pragma unroll
  for (int r = 0; r < 2; ++r) {
    const float* wr = Wrec + (size_t)(n0g + nq * 2 + r) * NN + kc * 32;
    #pragma unroll
    for (int j = 0; j < 8; ++j) wv[r][j] = *(const float4*)(wr + 4 * j);
  }
  // ---- W_in slice into LDS (swizzled slot per f4 group) ----
  for (int idx = tid; idx < NTL * FF; idx += 512) {
    const int n = idx >> 8, f = idx & 255;
    const int g = f >> 2, gs = g ^ ((g >> 3) & 7);
    wi[n * 260 + gs * 4 + (f & 3)] = Win[(size_t)(n0g + n) * FF + f];
  }
  // ---- per-n params + swizzled slot for finish threads (tid<256) ----
  float rA = 0.f, rIT = 0.f, rB = 0.f;
  int swn = 0;
  if (tid < 256) {
    const int n = n0g + (tid & 63);
    rA = Av[n]; rIT = 1.0f / tauv[n]; rB = bv[n];
    const int gg = n >> 2;
    swn = ((gg ^ ((gg >> 3) & 7)) << 2) | (n & 3);
  }
  for (int idx = tid; idx < 2048; idx += 512) lds[idx] = 0.f;  // x0 = 0 (A,B)

  // ---- thread-constant addressing ----
  const int sx = kc & 7;
  const int gb = (kc * 4) ^ ((kc >> 1) & 7);
  const float4* aq0 = (const float4*)xshA + kc * 8;
  const float4* aq1 = aq0 + 128;
  const float4* bq0 = (const float4*)xshB + kc * 8;
  const float4* bq1 = bq0 + 128;
  const float4* iq  = (const float4*)iro;           // rows at *65
  const float4* wq  = (const float4*)wi + (nq * 2) * 65;
  // stage map: thread covers mailbox entries {2tid, 2tid+1} = (b, n, n+1)
  const int sb = tid >> 8;
  const int sn = 2 * (tid & 255);
  const bool rem = (sn < n0g) || (sn >= n0g + NTL);  // remote segment?
  const int stg = sn >> 2;
  const int sts = ((stg ^ ((stg >> 3) & 7)) << 2) | (sn & 3);
  float* stwA = xshA + sb * 512 + sts;
  float* stwB = xshB + sb * 512 + sts;
  const int ment = sb * 512 + sn;                    // mailbox entry base
  __syncthreads();

  int v = 0;
  ull pA0 = 0, pA1 = 0, pB0 = 0, pB1 = 0;
  #pragma unroll 1
  for (int t = 0; t < TT; ++t) {
    // ---- stage 4 input rows (A0,A1,B0,B1; swizzled) + dt ----
    if (tid < 256) {
      const int row = tid >> 6, f4 = tid & 63;
      const int gsi = f4 ^ ((f4 >> 3) & 7);
      ((float4*)iro)[row * 65 + gsi] =
          *(const float4*)&I[((size_t)(4 * p + row) * TT + t) * FF + f4 * 4];
    }
    if (tid < 4) dts[tid] = DT[(size_t)(4 * p + tid) * TT + t] * (1.0f / KK);
    __syncthreads();

    // ---- input GEMV: 4 batch rows x 2 n, f in [16kc,16kc+16) ----
    {
      float a00=0.f,a01=0.f,a10=0.f,a11=0.f,a20=0.f,a21=0.f,a30=0.f,a31=0.f;
      #pragma unroll
      for (int j2 = 0; j2 < 4; ++j2) {
        const int gg = gb ^ j2;
        float4 w0 = wq[gg], w1 = wq[65 + gg];
        float4 x0 = iq[gg], x1 = iq[65 + gg], x2 = iq[130 + gg], x3 = iq[195 + gg];
        a00 += DOT4(w0, x0); a01 += DOT4(w1, x0);
        a10 += DOT4(w0, x1); a11 += DOT4(w1, x1);
        a20 += DOT4(w0, x2); a21 += DOT4(w1, x2);
        a30 += DOT4(w0, x3); a31 += DOT4(w1, x3);
      }
      const int pb = (nq * 2) * 17 + kc;
      par[pb]            = a00; par[pb + 17]        = a01;
      par[64 * 17 + pb]  = a10; par[64 * 17 + pb + 17]  = a11;
      par[128 * 17 + pb] = a20; par[128 * 17 + pb + 17] = a21;
      par[192 * 17 + pb] = a30; par[192 * 17 + pb + 17] = a31;
    }
    __syncthreads();
    float rInp = 0.f, dtk = 0.f;
    if (tid < 256) {
      float s = rB;
      #pragma unroll
      for (int c = 0; c < 16; ++c) s += par[tid * 17 + c];
      rInp = s;
      dtk = dts[tid >> 6];
    }
    // no barrier: BAR1 of kk=0 orders par reuse

    // ---- K unfolds, two streams interleaved ----
    #pragma unroll 1
    for (int kk = 0; kk < KK; ++kk) {
      ++v;  // producing version v for both streams

      // CHECK_A: verify prefetched x_A[v-1], stage remote into xshA
      if (v > 1 && rem) {
        const unsigned want = (unsigned)(v - 1);
        if ((unsigned)(pA0 >> 32) != want || (unsigned)(pA1 >> 32) != want) {
          const ull* q = mbx + (((size_t)btA * 2 + ((v - 1) & 1)) << 10) + ment;
          int guard = 1 << 14;  // hang-proof: deadlock -> bad data, visible
          while (((unsigned)(pA0 >> 32) != want ||
                  (unsigned)(pA1 >> 32) != want) && --guard) {
            __builtin_amdgcn_s_sleep(1);
            if ((unsigned)(pA0 >> 32) != want) pA0 = MLOAD(q);
            if ((unsigned)(pA1 >> 32) != want) pA1 = MLOAD(q + 1);
          }
        }
        stwA[0] = __uint_as_float((unsigned)pA0);
        stwA[1] = __uint_as_float((unsigned)pA1);
      }
      __syncthreads();                    // BAR1: xshA = x_A[v-1] complete

      if (v > 1 && rem) {                 // ISSUE_B: loads for x_B[v-1]
        const ull* q = mbx + (((size_t)btB * 2 + ((v - 1) & 1)) << 10) + ment;
        pB0 = MLOAD(q); pB1 = MLOAD(q + 1);   // drain at BAR2 (under GEMV_A)
      }
      // GEMV_A
      {
        float c00=0.f,c01=0.f,c10=0.f,c11=0.f;
        #pragma unroll
        for (int j = 0; j < 8; ++j) {
          float4 x0 = aq0[j ^ sx], x1 = aq1[j ^ sx];
          c00 += DOT4(wv[0][j], x0); c01 += DOT4(wv[1][j], x0);
          c10 += DOT4(wv[0][j], x1); c11 += DOT4(wv[1][j], x1);
        }
        const int pb = (nq * 2) * 17 + kc;
        par[pb]           = c00; par[pb + 17]           = c01;
        par[64 * 17 + pb] = c10; par[64 * 17 + pb + 17] = c11;
      }
      __syncthreads();                    // BAR2: parA ready

      // finish_A (tid<128)  ||  CHECK_B (rem threads)
      if (tid < 128) {
        float arg = rInp;
        #pragma unroll
        for (int c = 0; c < 16; ++c) arg += par[tid * 17 + c];
        const int b = tid >> 6, n = n0g + (tid & 63);
        float f  = tanhf(arg);
        float xo = xshA[b * 512 + swn];
        float xn = fmaf(dtk * f, rA, xo) / fmaf(dtk, rIT + f, 1.0f);
        xshA[b * 512 + swn] = xn;         // local bypass
        MSTORE(mbx + (((size_t)btA * 2 + (v & 1)) << 10) + b * 512 + n,
               ((ull)(unsigned)v << 32) | (ull)__float_as_uint(xn));
        if (kk == KK - 1)
          out[((size_t)(4 * p + b) * TT + t) * NN + n] = xn;
      }
      if (v > 1 && rem) {                 // CHECK_B: stage x_B[v-1]
        const unsigned want = (unsigned)(v - 1);
        if ((unsigned)(pB0 >> 32) != want || (unsigned)(pB1 >> 32) != want) {
          const ull* q = mbx + (((size_t)btB * 2 + ((v - 1) & 1)) << 10) + ment;
          int guard = 1 << 14;
          while (((unsigned)(pB0 >> 32) != want ||
                  (unsigned)(pB1 >> 32) != want) && --guard) {
            __builtin_amdgcn_s_sleep(1);
            if ((unsigned)(pB0 >> 32) != want) pB0 = MLOAD(q);
            if ((unsigned)(pB1 >> 32) != want) pB1 = MLOAD(q + 1);
          }
        }
        stwB[0] = __uint_as_float((unsigned)pB0);
        stwB[1] = __uint_as_float((unsigned)pB1);
      }
      __syncthreads();                    // BAR3: xshB = x_B[v-1] complete

      if (rem) {                          // ISSUE_A: loads for x_A[v]
        const ull* q = mbx + (((size_t)btA * 2 + (v & 1)) << 10) + ment;
        pA0 = MLOAD(q); pA1 = MLOAD(q + 1);   // drain at BAR4 (under GEMV_B)
      }
      // GEMV_B
      {
        float c00=0.f,c01=0.f,c10=0.f,c11=0.f;
        #pragma unroll
        for (int j = 0; j < 8; ++j) {
          float4 x0 = bq0[j ^ sx], x1 = bq1[j ^ sx];
          c00 += DOT4(wv[0][j], x0); c01 += DOT4(wv[1][j], x0);
          c10 += DOT4(wv[0][j], x1); c11 += DOT4(wv[1][j], x1);
        }
        const int pb = (128 + nq * 2) * 17 + kc;
        par[pb]           = c00; par[pb + 17]           = c01;
        par[64 * 17 + pb] = c10; par[64 * 17 + pb + 17] = c11;
      }
      __syncthreads();                    // BAR4: parB ready

      // finish_B (tid in [128,256)) — par flat index == tid
      if (tid >= 128 && tid < 256) {
        float arg = rInp;
        #pragma unroll
        for (int c = 0; c < 16; ++c) arg += par[tid * 17 + c];
        const int b = (tid >> 6) & 1, n = n0g + (tid & 63);
        float f  = tanhf(arg);
        float xo = xshB[b * 512 + swn];
        float xn = fmaf(dtk * f, rA, xo) / fmaf(dtk, rIT + f, 1.0f);
        xshB[b * 512 + swn] = xn;         // local bypass
        MSTORE(mbx + (((size_t)btB * 2 + (v & 1)) << 10) + b * 512 + n,
               ((ull)(unsigned)v << 32) | (ull)__float_as_uint(xn));
        if (kk == KK - 1)
          out[((size_t)(4 * p + 2 + b) * TT + t) * NN + n] = xn;
      }
      // no trailing barrier: next kk's CHECK_A writes disjoint xshA remote
      // slots; all other hazards ordered by BAR1..BAR4 of the next kk.
    }
  }
}

extern "C" void kernel_launch(void* const* d_in, const int* in_sizes, int n_in,
                              void* d_out, int out_size, void* d_ws, size_t ws_size,
                              hipStream_t stream) {
  const float* I    = (const float*)d_in[0];
  const float* DT   = (const float*)d_in[1];
  const float* Wrec = (const float*)d_in[2];
  const float* Win  = (const float*)d_in[3];
  const float* bv   = (const float*)d_in[4];
  const float* Av   = (const float*)d_in[5];
  const float* tauv = (const float*)d_in[6];
  float* out = (float*)d_out;
  ull* mbx = (ull*)d_ws;  // 64*2*2*512*8 B = 1 MB

  liquid_kernel<<<256, 512, 0, stream>>>(I, DT, Wrec, Win, bv, Av, tauv, mbx, out);
}

// Round 12
// 3360.751 us; speedup vs baseline: 1.4689x; 1.4689x over previous
//
#include <hip/hip_runtime.h>
#include <math.h>

typedef unsigned long long ull;

// LTC liquid scan — batch-amortized GEMM decomposition.
// Round-13: ROUND-4 EXACT BASE (best measured: 3474 us) + ONE change:
// XCD-CO-LOCATION of exchange groups. Rounds 8-11 proved the per-unfold
// exchange wait (~2.4K cy) resists traffic cuts (r8), placement (r9),
// detection cadence (r10), and cross-stream overlap (r11 — peers 4->8 made
// skew worse). Remaining lever: the RT itself. Each bt-group's mailbox is
// shared by exactly 4 blocks (4 nt tiles); default dispatch spreads them
// across 4 XCDs -> every poll/publish transits the device coherence point
// (~700-900 cy). Remap blockIdx (dispatch heuristic XCD = blk % 8,
// performance-only, protocol never assumes placement):
//   xcd = blk&7, slot = blk>>3, bt = xcd*8 + (slot>>2), nt = slot&3
// -> all 4 peers of each bt share one XCD; mailbox lines' only sharers are
// XCD-local -> agent loads can be served at XCD-L2 latency (~200 cy).
// Decisive signature: FETCH_SIZE collapse (polls leave the HBM books).
// If unchanged -> exchange RT is IC-pinned; this design's floor is ~3.4ms.
// Kept: BT=2/NTL=128 (4-peer minimum), 3-barrier unfold loop, batched
// sleep-paced re-poll with guard (hang -> passed:false), XOR f4 swizzle,
// W_rec slice in VGPRs (128 f/thread), W_in slice in LDS.

#define NN 512
#define FF 256
#define KK 6
#define TT 256
#define BT 2         // batches per tile
#define NTL 128      // neurons per tile

#define XROW 512     // xsh row pitch (dwords); conflicts handled by swizzle
#define IPITCH 260   // = 65 float4
#define WIPITCH 260  // = 65 float4
#define PPITCH 17

#define DOT4(a, v) ((a).x * (v).x + (a).y * (v).y + (a).z * (v).z + (a).w * (v).w)

__global__ __launch_bounds__(512, 2) void liquid_kernel(
    const float* __restrict__ I,     // [B][T][F]
    const float* __restrict__ DT,    // [B][T]
    const float* __restrict__ Wrec,  // [N][N]
    const float* __restrict__ Win,   // [N][F]
    const float* __restrict__ bv, const float* __restrict__ Av,
    const float* __restrict__ tauv,
    ull* __restrict__ mbx,           // [64 bt][2 slot][2 b][512 n] versioned
    float* __restrict__ out)         // [B][T][N]
{
  __shared__ __align__(16) float lds[39178];  // 153.0 KB -> 1 block/CU
  float* xsh = lds;                   // [2][512]  x_{jj-1}, swizzled f4 groups
  float* iro = lds + BT * XROW;       // [2][260]  input rows, swizzled
  float* wi  = iro + BT * IPITCH;     // [128][260] W_in slice, swizzled
  float* par = wi + NTL * WIPITCH;    // [256][17] k-chunk partials
  float* dts = par + 256 * PPITCH;    // [2] dt/K per batch

  const int blk = blockIdx.x;
  // XCD-co-location: dispatch heuristic XCD = blk % 8. All 4 nt-blocks of a
  // bt get the same (blk & 7) -> same XCD -> XCD-local mailbox sharing.
  const int xcd  = blk & 7;
  const int slot = blk >> 3;         // 0..31
  const int bt   = xcd * 8 + (slot >> 2);   // batch tile (64)
  const int nt   = slot & 3;         // neuron tile (4)
  const int tid = threadIdx.x;
  const int kc  = tid & 15;          // k-chunk (32 k each)
  const int nq  = tid >> 4;          // n-quad (4 n each), 0..31
  const int n0g = nt * NTL;          // global n base of this tile

  // ---- W_rec slice into VGPRs: wv[r][j] = Wrec[n0g+4nq+r][32kc+4j .. +3] ----
  float4 wv[4][8];
  #pragma unroll
  for (int r = 0; r < 4; ++r) {
    const float* wr = Wrec + (size_t)(n0g + nq * 4 + r) * NN + kc * 32;
    #pragma unroll
    for (int j = 0; j < 8; ++j) wv[r][j] = *(const float4*)(wr + 4 * j);
  }
  // ---- W_in slice into LDS (swizzled slot per float4 group) ----
  for (int idx = tid; idx < NTL * FF; idx += 512) {
    const int n = idx >> 8, f = idx & 255;
    const int g = f >> 2, gs = g ^ ((g >> 3) & 7);
    wi[n * WIPITCH + gs * 4 + (f & 3)] = Win[(size_t)(n0g + n) * FF + f];
  }
  // ---- per-(b,n) params + swizzled xo index for reduction threads ----
  float rA = 0.f, rIT = 0.f, rB = 0.f;
  int swn = 0;
  if (tid < 256) {
    const int rn = tid & 127;                       // local neuron
    const int n = n0g + rn;
    rA = Av[n]; rIT = 1.0f / tauv[n]; rB = bv[n];
    const int gg = n >> 2;                          // global f4 group
    swn = ((gg ^ ((gg >> 3) & 7)) << 2) | (n & 3);
  }
  for (int idx = tid; idx < BT * XROW; idx += 512) xsh[idx] = 0.f;  // x0=0

  // ---- thread-constant swizzled addressing (hoisted out of the t-loop) ----
  const int sx  = kc & 7;                           // xsh GEMV read sel
  const int gb  = (kc * 4) ^ ((kc >> 1) & 7);       // wi/iro read slot base
  const float4* xq0 = (const float4*)xsh + kc * 8;  // batch 0
  const float4* xq1 = xq0 + 128;                    // batch 1
  const float4* iq0 = (const float4*)iro;
  const float4* iq1 = iq0 + 65;
  const float4* wq  = (const float4*)wi + (nq * 4) * 65;
  // stage: thread handles mailbox entries {2tid, 2tid+1} -> (b, n, n+1)
  const int stb = tid >> 8;                         // staging batch row
  const int stn = 2 * (tid & 255);                  // global n (even)
  const int stg = stn >> 2;                         // logical f4 group
  float* stw = xsh + stb * XROW + ((stg ^ ((stg >> 3) & 7)) << 2) + (stn & 3);
  __syncthreads();

  int jj = 0;
  #pragma unroll 1
  for (int t = 0; t < TT; ++t) {
    // ---- stage input rows (swizzled) + dt ----
    if (tid < 2 * 64) {
      const int b = tid >> 6, f4 = tid & 63;
      const int gsi = f4 ^ ((f4 >> 3) & 7);
      ((float4*)iro)[b * 65 + gsi] =
          *(const float4*)&I[((size_t)(bt * BT + b) * TT + t) * FF + f4 * 4];
    }
    if (tid < BT) dts[tid] = DT[(size_t)(bt * BT + tid) * TT + t] * (1.0f / KK);
    __syncthreads();

    // ---- input GEMV partials: inp[b][n] over f in [16kc,16kc+16) ----
    {
      float ai0[4] = {0.f, 0.f, 0.f, 0.f}, ai1[4] = {0.f, 0.f, 0.f, 0.f};
      #pragma unroll
      for (int j2 = 0; j2 < 4; ++j2) {
        const int gg = gb ^ j2;                     // swizzled slot
        float4 w0 = wq[0 * 65 + gg];
        float4 w1 = wq[1 * 65 + gg];
        float4 w2 = wq[2 * 65 + gg];
        float4 w3 = wq[3 * 65 + gg];
        float4 xa = iq0[gg];
        float4 xb = iq1[gg];
        ai0[0] += DOT4(w0, xa); ai0[1] += DOT4(w1, xa);
        ai0[2] += DOT4(w2, xa); ai0[3] += DOT4(w3, xa);
        ai1[0] += DOT4(w0, xb); ai1[1] += DOT4(w1, xb);
        ai1[2] += DOT4(w2, xb); ai1[3] += DOT4(w3, xb);
      }
      #pragma unroll
      for (int r = 0; r < 4; ++r) {
        par[(0 * NTL + nq * 4 + r) * PPITCH + kc] = ai0[r];
        par[(1 * NTL + nq * 4 + r) * PPITCH + kc] = ai1[r];
      }
    }
    __syncthreads();
    float rInp = 0.f;
    if (tid < 256) {
      float s = rB;
      #pragma unroll
      for (int c = 0; c < 16; ++c) s += par[tid * PPITCH + c];
      rInp = s;
    }
    __syncthreads();  // par free for unfold reuse

    // ---- K unfolds ----
    #pragma unroll 1
    for (int kk = 0; kk < KK; ++kk) {
      ++jj;  // producing x_jj; consuming x_{jj-1}

      // stage x_{jj-1}[2][512] from mailbox (skip jj==1: x0=0 already in xsh)
      if (jj > 1) {
        const ull* src = mbx + (((size_t)bt * 2 + ((jj - 1) & 1)) << 10);
        const ull* p = src + 2 * tid;
        const unsigned want = (unsigned)(jj - 1);
        ull v0 = __hip_atomic_load(p,     __ATOMIC_RELAXED, __HIP_MEMORY_SCOPE_AGENT);
        ull v1 = __hip_atomic_load(p + 1, __ATOMIC_RELAXED, __HIP_MEMORY_SCOPE_AGENT);
        int guard = 1 << 16;   // hang-proof: deadlock -> bad data, visible
        while (((unsigned)(v0 >> 32) != want || (unsigned)(v1 >> 32) != want)
               && --guard) {
          __builtin_amdgcn_s_sleep(1);
          if ((unsigned)(v0 >> 32) != want)
            v0 = __hip_atomic_load(p,     __ATOMIC_RELAXED, __HIP_MEMORY_SCOPE_AGENT);
          if ((unsigned)(v1 >> 32) != want)
            v1 = __hip_atomic_load(p + 1, __ATOMIC_RELAXED, __HIP_MEMORY_SCOPE_AGENT);
        }
        stw[0] = __uint_as_float((unsigned)v0);
        stw[1] = __uint_as_float((unsigned)v1);
      }
      __syncthreads();

      // GEMV: acc[b][n] partial over k in [32kc, 32kc+32), W from VGPRs.
      // slot (j ^ sx) holds logical group j -> pairs with wv[r][j].
      {
        float acc0[4] = {0.f, 0.f, 0.f, 0.f}, acc1[4] = {0.f, 0.f, 0.f, 0.f};
        #pragma unroll
        for (int j = 0; j < 8; ++j) {
          float4 xv = xq0[j ^ sx];
          acc0[0] += DOT4(wv[0][j], xv); acc0[1] += DOT4(wv[1][j], xv);
          acc0[2] += DOT4(wv[2][j], xv); acc0[3] += DOT4(wv[3][j], xv);
        }
        #pragma unroll
        for (int j = 0; j < 8; ++j) {
          float4 xv = xq1[j ^ sx];
          acc1[0] += DOT4(wv[0][j], xv); acc1[1] += DOT4(wv[1][j], xv);
          acc1[2] += DOT4(wv[2][j], xv); acc1[3] += DOT4(wv[3][j], xv);
        }
        #pragma unroll
        for (int r = 0; r < 4; ++r) {
          par[(0 * NTL + nq * 4 + r) * PPITCH + kc] = acc0[r];
          par[(1 * NTL + nq * 4 + r) * PPITCH + kc] = acc1[r];
        }
      }
      __syncthreads();

      // reduce + nonlinearity + publish (+ output on last unfold)
      if (tid < 256) {
        float arg = rInp;
        #pragma unroll
        for (int c = 0; c < 16; ++c) arg += par[tid * PPITCH + c];
        const int rb = tid >> 7, rn = tid & 127;
        float f   = tanhf(arg);
        float dtk = dts[rb];
        float xo  = xsh[rb * XROW + swn];
        float xn  = fmaf(dtk * f, rA, xo) / fmaf(dtk, rIT + f, 1.0f);
        ull w = ((ull)(unsigned)jj << 32) | (ull)__float_as_uint(xn);
        __hip_atomic_store(mbx + (((size_t)bt * 2 + (jj & 1)) << 10) + rb * NN + n0g + rn,
                           w, __ATOMIC_RELAXED, __HIP_MEMORY_SCOPE_AGENT);
        if (kk == KK - 1)
          out[((size_t)(bt * BT + rb) * TT + t) * NN + n0g + rn] = xn;
      }
      __syncthreads();  // xsh/par reads done before next stage overwrites
    }
  }
}

extern "C" void kernel_launch(void* const* d_in, const int* in_sizes, int n_in,
                              void* d_out, int out_size, void* d_ws, size_t ws_size,
                              hipStream_t stream) {
  const float* I    = (const float*)d_in[0];
  const float* DT   = (const float*)d_in[1];
  const float* Wrec = (const float*)d_in[2];
  const float* Win  = (const float*)d_in[3];
  const float* bv   = (const float*)d_in[4];
  const float* Av   = (const float*)d_in[5];
  const float* tauv = (const float*)d_in[6];
  float* out = (float*)d_out;
  ull* mbx = (ull*)d_ws;  // 64*2*2*512*8 B = 1 MB

  liquid_kernel<<<256, 512, 0, stream>>>(I, DT, Wrec, Win, bv, Av, tauv, mbx, out);
}